// Round 11
// baseline (271.058 us; speedup 1.0000x reference)
//
#include <hip/hip_runtime.h>

#define N_NODES 50000
#define N_EDGES 800000
#define NPAD 50176   // 49 * 1024, padded histogram size

typedef float f32x4 __attribute__((ext_vector_type(4)));
typedef float f32x2 __attribute__((ext_vector_type(2)));
typedef short bf16x8 __attribute__((ext_vector_type(8)));

__device__ __forceinline__ float fast_tanh(float x) {
  // tanh(x) = 1 - 2/(exp(2x)+1); v_rcp_f32 (1 ulp) instead of IEEE div sequence
  float e = __expf(2.0f * x);
  float r;
  asm("v_rcp_f32 %0, %1" : "=v"(r) : "v"(e + 1.0f));
  return fmaf(-2.0f, r, 1.0f);
}

__device__ __forceinline__ unsigned short f2bf_rne(float x) {
  unsigned u = __float_as_uint(x);
  unsigned r = u + 0x7FFFu + ((u >> 16) & 1u);
  return (unsigned short)(r >> 16);
}

// ---- pack a 64x64 f32 weight (row-major W[k][col]) into MFMA B-fragment order, bf16.
// 256-thread version: each thread packs fragments tid and tid+256.
__device__ __forceinline__ void packW256(const float* __restrict__ W,
                                         unsigned short* __restrict__ dst, int tid) {
  #pragma unroll
  for (int hh = 0; hh < 2; ++hh) {
    int t = tid + hh * 256;
    int ks = t >> 8, ct = (t >> 6) & 3, lane = t & 63;
    int k0 = ks * 32 + ((lane >> 4) << 3);
    int col = ct * 16 + (lane & 15);
    const float* src = W + k0 * 64 + col;
    unsigned u[4];
    #pragma unroll
    for (int jj = 0; jj < 4; ++jj) {
      float v0 = src[(2 * jj) * 64];
      float v1 = src[(2 * jj + 1) * 64];
      asm("v_cvt_pk_bf16_f32 %0, %1, %2" : "=v"(u[jj]) : "v"(v0), "v"(v1));
    }
    *(uint4*)(dst + (size_t)t * 8) = make_uint4(u[0], u[1], u[2], u[3]);
  }
}

// ---- one 64x64x64 GEMM step on MFMA: acc[ct] += ActIn(16 rows of wave w) @ Bpk
// ActIn: bf16 [64][64], col XOR-swizzled by ((row&7)<<3).
__device__ __forceinline__ void mfma_gemm(const unsigned short* __restrict__ actIn,
                                          const unsigned short* __restrict__ bpk,
                                          int w, int l, f32x4 acc[4]) {
  int m = l & 15, s = l >> 4;
  int row = w * 16 + m;
  int sw = (m & 7) << 3;
  #pragma unroll
  for (int ks = 0; ks < 2; ++ks) {
    bf16x8 a = *(const bf16x8*)(actIn + row * 64 + ((ks * 32 + s * 8) ^ sw));
    #pragma unroll
    for (int ct = 0; ct < 4; ++ct) {
      bf16x8 b = *(const bf16x8*)(bpk + ((size_t)((ks * 4 + ct) * 64 + l)) * 8);
      acc[ct] = __builtin_amdgcn_mfma_f32_16x16x32_bf16(a, b, acc[ct], 0, 0, 0);
    }
  }
}

// ---- write MFMA C (col=ct*16+m, row=s*4+r) to a bf16 act tile (swizzled), opt tanh
__device__ __forceinline__ void store_act(unsigned short* __restrict__ actOut,
                                          int w, int l, const f32x4 acc[4],
                                          bool do_tanh) {
  int m = l & 15, s = l >> 4;
  #pragma unroll
  for (int ct = 0; ct < 4; ++ct) {
    #pragma unroll
    for (int r = 0; r < 4; ++r) {
      int row = w * 16 + s * 4 + r;
      float v = acc[ct][r];
      if (do_tanh) v = fast_tanh(v);
      actOut[row * 64 + ((ct * 16 + m) ^ ((row & 7) << 3))] = f2bf_rne(v);
    }
  }
}

// ---------- D1: hist + prep (512 threads).  blocks [0,1563): hist ; [1563,1636): prep
__global__ __launch_bounds__(512) void hist_prep_kernel(
    const int* __restrict__ idx_j,
    const float* __restrict__ piW2, const float* __restrict__ pib1,
    const float* __restrict__ pib2,
    const float* __restrict__ piW3, const float* __restrict__ iiW1,
    const float* __restrict__ iiW2,
    int* __restrict__ counts, float* __restrict__ b12,
    unsigned short* __restrict__ Bpack, unsigned short* __restrict__ W2pack) {
  int bid = blockIdx.x;
  int tid = threadIdx.x;
  if (bid < 1563) {  // hist
    int e = bid * 512 + tid;
    if (e < N_EDGES) atomicAdd(&counts[idx_j[e]], 1);
    return;
  }
  int gid = (bid - 1563) * 512 + tid;
  if (gid < 32768) {
    int j = gid & 7;
    int lane = (gid >> 3) & 63;
    int ct = (gid >> 9) & 3;
    int ks = gid >> 11;
    int kidx = ks * 32 + ((lane >> 4) << 3) + j;
    int col = ct * 16 + (lane & 15);
    int k = kidx >> 3, b = kidx & 7;
    float acc = 0.f;
    #pragma unroll 8
    for (int mm = 0; mm < 64; ++mm)
      acc = fmaf(piW3[k * 512 + mm * 8 + b], iiW1[mm * 64 + col], acc);
    Bpack[gid] = f2bf_rne(acc);
  } else if (gid < 32832) {
    int c = gid - 32768;
    float acc = pib2[c];
    for (int k = 0; k < 64; ++k) acc = fmaf(pib1[k], piW2[k * 64 + c], acc);
    b12[c] = acc;
  } else if (gid < 36928) {
    int g2 = gid - 32832;
    int j = g2 & 7;
    int lane = (g2 >> 3) & 63;
    int ct = (g2 >> 9) & 3;
    int ks = g2 >> 11;
    int kidx = ks * 32 + ((lane >> 4) << 3) + j;
    int col = ct * 16 + (lane & 15);
    W2pack[g2] = f2bf_rne(iiW2[kidx * 64 + col]);
  }
}

// ---------- D2: single-dispatch exclusive scan (block b scans chunk b; redundant base)
__global__ __launch_bounds__(1024) void scan_kernel(
    const int* __restrict__ counts, int* __restrict__ cursors) {
  __shared__ int buf[1024];
  __shared__ int red[16];
  int b = blockIdx.x, tid = threadIdx.x;
  int idx = b * 1024 + tid;
  int v = counts[idx];
  buf[tid] = v;
  int partial = 0;
  for (int i = tid; i < b * 1024; i += 1024) partial += counts[i];
  #pragma unroll
  for (int off = 32; off >= 1; off >>= 1) partial += __shfl_down(partial, off, 64);
  if ((tid & 63) == 0) red[tid >> 6] = partial;
  __syncthreads();
  for (int off = 1; off < 1024; off <<= 1) {
    int t = (tid >= off) ? buf[tid - off] : 0;
    __syncthreads();
    buf[tid] += t;
    __syncthreads();
  }
  int base = 0;
  #pragma unroll
  for (int i = 0; i < 16; ++i) base += red[i];
  cursors[idx] = base + buf[tid] - v;
}

// ---------- D3: node MLP (MFMA, 64 nodes / 256-thread block) fused with sort-scatter.
// blocks [0,782): node -> qa,qb ; blocks [782,3907): scatter edges into j-sorted order
__global__ __launch_bounds__(256) void node_scatter_kernel(
    const float* __restrict__ p,
    const int* __restrict__ idx_i, const int* __restrict__ idx_j,
    const float* __restrict__ ppW1, const float* __restrict__ ppb1,
    const float* __restrict__ ppW2, const float* __restrict__ ppb2,
    const float* __restrict__ piW1, const float* __restrict__ piW2,
    int* __restrict__ cursors,
    float* __restrict__ qa, float* __restrict__ qb,
    int2* __restrict__ sorted_ij, int* __restrict__ sorted_e) {
  int bid = blockIdx.x;
  int tid = threadIdx.x;

  if (bid >= 782) {  // ---------------- scatter
    int e = (bid - 782) * 256 + tid;
    if (e < N_EDGES) {
      int j = idx_j[e];
      int pos = atomicAdd(&cursors[j], 1);
      sorted_ij[pos] = make_int2(idx_i[e], j);
      sorted_e[pos] = e;
    }
    return;
  }

  // ---------------- node (MFMA), 64 nodes, 4 waves
  __shared__ __align__(16) unsigned short sBpk[2][4096];  // 16 KB
  __shared__ __align__(16) unsigned short sAct[2][4096];  // 16 KB ([64][64] each)

  int w = tid >> 6, l = tid & 63;
  int m = l & 15;
  int nb0 = bid * 64;

  for (int t = tid; t < 1024; t += 256) {
    int row = t >> 4, q = t & 15;
    int g = nb0 + row;
    float4 v = make_float4(0.f, 0.f, 0.f, 0.f);
    if (g < N_NODES) v = ((const float4*)p)[g * 16 + q];
    unsigned u0, u1;
    asm("v_cvt_pk_bf16_f32 %0, %1, %2" : "=v"(u0) : "v"(v.x), "v"(v.y));
    asm("v_cvt_pk_bf16_f32 %0, %1, %2" : "=v"(u1) : "v"(v.z), "v"(v.w));
    int sw = (row & 7) << 3;
    *(uint2*)(&sAct[0][row * 64 + ((q * 4) ^ sw)]) = make_uint2(u0, u1);
  }
  packW256(ppW1, sBpk[0], tid);
  packW256(ppW2, sBpk[1], tid);
  __syncthreads();

  f32x4 acc[4];
  // A: h = tanh(X@ppW1 + b1) -> sAct[1]
  #pragma unroll
  for (int ct = 0; ct < 4; ++ct) {
    float bv = ppb1[ct * 16 + m];
    acc[ct] = (f32x4){bv, bv, bv, bv};
  }
  mfma_gemm(sAct[0], sBpk[0], w, l, acc);
  store_act(sAct[1], w, l, acc, true);
  __syncthreads();

  // B: p1 = h@ppW2 + b2 -> sAct[0]
  #pragma unroll
  for (int ct = 0; ct < 4; ++ct) {
    float bv = ppb2[ct * 16 + m];
    acc[ct] = (f32x4){bv, bv, bv, bv};
  }
  mfma_gemm(sAct[1], sBpk[1], w, l, acc);
  store_act(sAct[0], w, l, acc, false);
  __syncthreads();

  packW256(piW1, sBpk[0], tid);
  packW256(piW2, sBpk[1], tid);
  __syncthreads();

  // C: t1 = p1@piW1a -> sAct[1]
  #pragma unroll
  for (int ct = 0; ct < 4; ++ct) acc[ct] = (f32x4){0.f, 0.f, 0.f, 0.f};
  mfma_gemm(sAct[0], sBpk[0], w, l, acc);
  store_act(sAct[1], w, l, acc, false);
  __syncthreads();

  // E: qa = t1@piW2 -> global ; repack slot0 = piW1b
  #pragma unroll
  for (int ct = 0; ct < 4; ++ct) acc[ct] = (f32x4){0.f, 0.f, 0.f, 0.f};
  mfma_gemm(sAct[1], sBpk[1], w, l, acc);
  {
    int s = l >> 4;
    #pragma unroll
    for (int ct = 0; ct < 4; ++ct)
      #pragma unroll
      for (int r = 0; r < 4; ++r) {
        int rg = nb0 + w * 16 + s * 4 + r;
        if (rg < N_NODES) qa[(size_t)rg * 64 + ct * 16 + m] = acc[ct][r];
      }
  }
  packW256(piW1 + 4096, sBpk[0], tid);
  __syncthreads();

  // D: t2 = p1@piW1b -> sAct[1]
  #pragma unroll
  for (int ct = 0; ct < 4; ++ct) acc[ct] = (f32x4){0.f, 0.f, 0.f, 0.f};
  mfma_gemm(sAct[0], sBpk[0], w, l, acc);
  store_act(sAct[1], w, l, acc, false);
  __syncthreads();

  // F: qb = t2@piW2 -> global
  #pragma unroll
  for (int ct = 0; ct < 4; ++ct) acc[ct] = (f32x4){0.f, 0.f, 0.f, 0.f};
  mfma_gemm(sAct[1], sBpk[1], w, l, acc);
  {
    int s = l >> 4;
    #pragma unroll
    for (int ct = 0; ct < 4; ++ct)
      #pragma unroll
      for (int r = 0; r < 4; ++r) {
        int rg = nb0 + w * 16 + s * 4 + r;
        if (rg < N_NODES) qb[(size_t)rg * 64 + ct * 16 + m] = acc[ct][r];
      }
  }
}

// ---------- D4: edge (j-sorted), 1024 threads = 16 waves, 256 edges/block.
// Round-9 proven structure (all barriers); only the A-pack uses v_pk_mul_f32.
__global__ __launch_bounds__(1024, 8) void edge_kernel(
    const int2* __restrict__ sorted_ij, const int* __restrict__ sorted_e,
    const float* __restrict__ basis,
    const float* __restrict__ qa, const float* __restrict__ qb,
    const float* __restrict__ b12,
    const unsigned short* __restrict__ Bpack,
    const unsigned short* __restrict__ W2pack,
    const float* __restrict__ iib1, const float* __restrict__ iib2,
    float* __restrict__ out) {
  __shared__ __align__(16) unsigned short sB[32768];  // 64 KB
  float* sH2 = (float*)sB;
  unsigned short* sT = sB;
  float* sF = (float*)sB;

  int tid = threadIdx.x;
  int e0 = blockIdx.x * 256;
  int w = tid >> 6, l = tid & 63;
  int m = l & 15, s = l >> 4;
  int eloc = w * 16 + m;
  int swz = (eloc & 7) << 3;

  // ---- issue long-latency loads first (T14): Bpack (L2) + basis (random)
  const uint4* gB = (const uint4*)Bpack;
  uint4 bp0 = gB[tid];
  uint4 bp1 = gB[tid + 1024];
  uint4 bp2 = gB[tid + 2048];
  uint4 bp3 = gB[tid + 3072];
  int eorig = sorted_e[e0 + eloc];
  const float4* bpt = (const float4*)(basis + (size_t)eorig * 8);
  float4 bas01 = bpt[0];
  float4 bas23 = bpt[1];

  // ---- phase 0: gather h2 into LDS (f32, XOR-swizzled). qb rows L1-hot (sorted j).
  for (int t = tid; t < 4096; t += 1024) {
    int e = t >> 4, q = t & 15;
    int2 se = sorted_ij[e0 + e];
    float4 va = ((const float4*)qa)[se.x * 16 + q];
    float4 vb = ((const float4*)qb)[se.y * 16 + q];
    float4 vc = ((const float4*)b12)[q];
    float4 h;
    h.x = va.x + vb.x + vc.x;
    h.y = va.y + vb.y + vc.y;
    h.z = va.z + vb.z + vc.z;
    h.w = va.w + vb.w + vc.w;
    int dw = e * 64 + ((q * 4) ^ ((e & 7) << 3));
    *((float4*)(sH2 + dw)) = h;
  }
  __syncthreads();

  float h2r[16];
  #pragma unroll
  for (int t = 0; t < 16; ++t) h2r[t] = sH2[eloc * 64 + ((t * 4 + s) ^ swz)];

  f32x2 bas2[4];
  bas2[0] = (f32x2){bas01.x, bas01.y};
  bas2[1] = (f32x2){bas01.z, bas01.w};
  bas2[2] = (f32x2){bas23.x, bas23.y};
  bas2[3] = (f32x2){bas23.z, bas23.w};
  __syncthreads();  // all h2 reads done before Bpack overwrite

  // ---- write prefetched Bpack into LDS
  {
    uint4* d = (uint4*)sB;
    d[tid] = bp0;
    d[tid + 1024] = bp1;
    d[tid + 2048] = bp2;
    d[tid + 3072] = bp3;
  }
  __syncthreads();

  f32x4 c0, c1, c2, c3;
  {
    float v0 = iib1[m], v1 = iib1[16 + m], v2 = iib1[32 + m], v3 = iib1[48 + m];
    c0 = (f32x4){v0, v0, v0, v0};
    c1 = (f32x4){v1, v1, v1, v1};
    c2 = (f32x4){v2, v2, v2, v2};
    c3 = (f32x4){v3, v3, v3, v3};
  }

  // ---- main K-loop: 16 K-steps x 4 col-tiles; A-pack = 4 pk_mul + 4 cvt_pk
  const bf16x8* Bl = (const bf16x8*)sB;
  #pragma unroll
  for (int ks = 0; ks < 16; ++ks) {
    bf16x8 B0 = Bl[(ks * 4 + 0) * 64 + l];
    bf16x8 B1 = Bl[(ks * 4 + 1) * 64 + l];
    bf16x8 B2 = Bl[(ks * 4 + 2) * 64 + l];
    bf16x8 B3 = Bl[(ks * 4 + 3) * 64 + l];
    float hv = h2r[ks];
    f32x2 hv2 = (f32x2){hv, hv};
    union { unsigned u[4]; bf16x8 v; } A;
    #pragma unroll
    for (int j = 0; j < 4; ++j) {
      f32x2 pr = hv2 * bas2[j];  // v_pk_mul_f32
      asm("v_cvt_pk_bf16_f32 %0, %1, %2" : "=v"(A.u[j]) : "v"(pr[0]), "v"(pr[1]));
    }
    c0 = __builtin_amdgcn_mfma_f32_16x16x32_bf16(A.v, B0, c0, 0, 0, 0);
    c1 = __builtin_amdgcn_mfma_f32_16x16x32_bf16(A.v, B1, c1, 0, 0, 0);
    c2 = __builtin_amdgcn_mfma_f32_16x16x32_bf16(A.v, B2, c2, 0, 0, 0);
    c3 = __builtin_amdgcn_mfma_f32_16x16x32_bf16(A.v, B3, c3, 0, 0, 0);
  }
  __syncthreads();  // all waves done reading Bpack

  // ---- tanh -> t tile (bf16). D layout: col = ct*16+m, row(local) = s*4+r
  #pragma unroll
  for (int r = 0; r < 4; ++r) {
    int row = w * 16 + s * 4 + r;
    sT[row * 72 + 0 * 16 + m] = f2bf_rne(fast_tanh(c0[r]));
    sT[row * 72 + 1 * 16 + m] = f2bf_rne(fast_tanh(c1[r]));
    sT[row * 72 + 2 * 16 + m] = f2bf_rne(fast_tanh(c2[r]));
    sT[row * 72 + 3 * 16 + m] = f2bf_rne(fast_tanh(c3[r]));
  }
  __syncthreads();

  // ---- second GEMM: i2 = t @ ii_W2 + ii_b2 (K=64: 2 K-steps x 4 col-tiles)
  f32x4 d0, d1, d2, d3;
  {
    float v0 = iib2[m], v1 = iib2[16 + m], v2 = iib2[32 + m], v3 = iib2[48 + m];
    d0 = (f32x4){v0, v0, v0, v0};
    d1 = (f32x4){v1, v1, v1, v1};
    d2 = (f32x4){v2, v2, v2, v2};
    d3 = (f32x4){v3, v3, v3, v3};
  }
  const bf16x8* Wl = (const bf16x8*)W2pack;
  #pragma unroll
  for (int ks = 0; ks < 2; ++ks) {
    bf16x8 Af = *(const bf16x8*)(sT + eloc * 72 + ks * 32 + s * 8);
    d0 = __builtin_amdgcn_mfma_f32_16x16x32_bf16(Af, Wl[(ks * 4 + 0) * 64 + l], d0, 0, 0, 0);
    d1 = __builtin_amdgcn_mfma_f32_16x16x32_bf16(Af, Wl[(ks * 4 + 1) * 64 + l], d1, 0, 0, 0);
    d2 = __builtin_amdgcn_mfma_f32_16x16x32_bf16(Af, Wl[(ks * 4 + 2) * 64 + l], d2, 0, 0, 0);
    d3 = __builtin_amdgcn_mfma_f32_16x16x32_bf16(Af, Wl[(ks * 4 + 3) * 64 + l], d3, 0, 0, 0);
  }

  // ---- phase 3: run-aggregated scatter (two 128-edge halves through LDS)
  #pragma unroll
  for (int h = 0; h < 2; ++h) {
    __syncthreads();
    if ((w >> 3) == h) {
      int wl = w & 7;
      #pragma unroll
      for (int r = 0; r < 4; ++r) {
        int row = wl * 16 + s * 4 + r;
        sF[row * 68 + 0  + m] = d0[r];
        sF[row * 68 + 16 + m] = d1[r];
        sF[row * 68 + 32 + m] = d2[r];
        sF[row * 68 + 48 + m] = d3[r];
      }
    }
    __syncthreads();
    {
      int base_e = e0 + h * 128 + w * 8;
      float acc = sF[(w * 8) * 68 + l];
      int cur_j = sorted_ij[base_e].y;
      #pragma unroll
      for (int rr = 1; rr < 8; ++rr) {
        int nj = sorted_ij[base_e + rr].y;
        float v = sF[(w * 8 + rr) * 68 + l];
        if (nj == cur_j) {
          acc += v;
        } else {
          atomicAdd(&out[(size_t)cur_j * 64 + l], acc);
          acc = v;
          cur_j = nj;
        }
      }
      atomicAdd(&out[(size_t)cur_j * 64 + l], acc);
    }
  }
}

extern "C" void kernel_launch(void* const* d_in, const int* in_sizes, int n_in,
                              void* d_out, int out_size, void* d_ws, size_t ws_size,
                              hipStream_t stream) {
  const float* p     = (const float*)d_in[0];
  const int*   idx_i = (const int*)d_in[1];
  const int*   idx_j = (const int*)d_in[2];
  const float* basis = (const float*)d_in[3];
  const float* ppW1  = (const float*)d_in[4];
  const float* ppb1  = (const float*)d_in[5];
  const float* ppW2  = (const float*)d_in[6];
  const float* ppb2  = (const float*)d_in[7];
  const float* piW1  = (const float*)d_in[8];
  const float* pib1  = (const float*)d_in[9];
  const float* piW2  = (const float*)d_in[10];
  const float* pib2  = (const float*)d_in[11];
  const float* piW3  = (const float*)d_in[12];
  const float* iiW1  = (const float*)d_in[13];
  const float* iib1  = (const float*)d_in[14];
  const float* iiW2  = (const float*)d_in[15];
  const float* iib2  = (const float*)d_in[16];

  float* ws  = (float*)d_ws;
  float* qa  = ws;                          // 3,200,000 f
  float* qb  = ws + 3200000;                // 3,200,000 f
  float* b12 = ws + 6400000;                // 64 f
  unsigned short* Bpack  = (unsigned short*)(ws + 6400064);   // 32768 bf16 (16384 f)
  unsigned short* W2pack = (unsigned short*)(ws + 6416448);   // 4096 bf16 (2048 f)
  int* counts    = (int*)(ws + 6418496);    // NPAD ints
  int* cursors   = (int*)(ws + 6468672);    // NPAD ints
  int2* sorted_ij = (int2*)(ws + 6518848);  // 800000 int2 (8B-aligned)
  int* sorted_e   = (int*)(ws + 8118848);   // 800000 ints (end ~35.7 MB)

  hipMemsetAsync(d_out, 0, (size_t)out_size * sizeof(float), stream);
  hipMemsetAsync(counts, 0, (size_t)NPAD * sizeof(int), stream);
  hist_prep_kernel<<<1636, 512, 0, stream>>>(idx_j, piW2, pib1, pib2,
                                             piW3, iiW1, iiW2,
                                             counts, b12, Bpack, W2pack);
  scan_kernel<<<49, 1024, 0, stream>>>(counts, cursors);
  node_scatter_kernel<<<3907, 256, 0, stream>>>(p, idx_i, idx_j,
                                                ppW1, ppb1, ppW2, ppb2,
                                                piW1, piW2, cursors,
                                                qa, qb, sorted_ij, sorted_e);
  edge_kernel<<<3125, 1024, 0, stream>>>(sorted_ij, sorted_e, basis,
                                         qa, qb, b12, Bpack, W2pack,
                                         iib1, iib2, (float*)d_out);
}

// Round 12
// 270.035 us; speedup vs baseline: 1.0038x; 1.0038x over previous
//
#include <hip/hip_runtime.h>

#define N_NODES 50000
#define N_EDGES 800000
#define NPAD 50176   // 49 * 1024, padded histogram size

typedef float f32x4 __attribute__((ext_vector_type(4)));
typedef float f32x2 __attribute__((ext_vector_type(2)));
typedef short bf16x8 __attribute__((ext_vector_type(8)));

__device__ __forceinline__ float fast_tanh(float x) {
  // tanh(x) = 1 - 2/(exp(2x)+1); v_rcp_f32 (1 ulp) instead of IEEE div sequence
  float e = __expf(2.0f * x);
  float r;
  asm("v_rcp_f32 %0, %1" : "=v"(r) : "v"(e + 1.0f));
  return fmaf(-2.0f, r, 1.0f);
}

__device__ __forceinline__ unsigned short f2bf_rne(float x) {
  unsigned u = __float_as_uint(x);
  unsigned r = u + 0x7FFFu + ((u >> 16) & 1u);
  return (unsigned short)(r >> 16);
}

// ---- pack a 64x64 f32 weight (row-major W[k][col]) into MFMA B-fragment order, bf16
// one thread packs one 8-entry fragment slot (tid in [0,512)).
__device__ __forceinline__ void packW(const float* __restrict__ W,
                                      unsigned short* __restrict__ dst, int tid) {
  int ks = tid >> 8, ct = (tid >> 6) & 3, lane = tid & 63;
  int k0 = ks * 32 + ((lane >> 4) << 3);
  int col = ct * 16 + (lane & 15);
  const float* src = W + k0 * 64 + col;
  unsigned u[4];
  #pragma unroll
  for (int jj = 0; jj < 4; ++jj) {
    float v0 = src[(2 * jj) * 64];
    float v1 = src[(2 * jj + 1) * 64];
    asm("v_cvt_pk_bf16_f32 %0, %1, %2" : "=v"(u[jj]) : "v"(v0), "v"(v1));
  }
  *(uint4*)(dst + (size_t)tid * 8) = make_uint4(u[0], u[1], u[2], u[3]);
}

// ---- one 128x64x64 GEMM step on MFMA: acc[ct] += ActIn(16 rows of wave w) @ Bpk
__device__ __forceinline__ void mfma_gemm(const unsigned short* __restrict__ actIn,
                                          const unsigned short* __restrict__ bpk,
                                          int w, int l, f32x4 acc[4]) {
  int m = l & 15, s = l >> 4;
  int row = w * 16 + m;
  int sw = (m & 7) << 3;
  #pragma unroll
  for (int ks = 0; ks < 2; ++ks) {
    bf16x8 a = *(const bf16x8*)(actIn + row * 64 + ((ks * 32 + s * 8) ^ sw));
    #pragma unroll
    for (int ct = 0; ct < 4; ++ct) {
      bf16x8 b = *(const bf16x8*)(bpk + ((size_t)((ks * 4 + ct) * 64 + l)) * 8);
      acc[ct] = __builtin_amdgcn_mfma_f32_16x16x32_bf16(a, b, acc[ct], 0, 0, 0);
    }
  }
}

// ---- write MFMA C (col=ct*16+m, row=s*4+r) to a bf16 act tile (swizzled), opt tanh
__device__ __forceinline__ void store_act(unsigned short* __restrict__ actOut,
                                          int w, int l, const f32x4 acc[4],
                                          bool do_tanh) {
  int m = l & 15, s = l >> 4;
  #pragma unroll
  for (int ct = 0; ct < 4; ++ct) {
    #pragma unroll
    for (int r = 0; r < 4; ++r) {
      int row = w * 16 + s * 4 + r;
      float v = acc[ct][r];
      if (do_tanh) v = fast_tanh(v);
      actOut[row * 64 + ((ct * 16 + m) ^ ((row & 7) << 3))] = f2bf_rne(v);
    }
  }
}

// ---------- D1: hist + prep (512 threads).  blocks [0,1563): hist ; [1563,1636): prep
__global__ __launch_bounds__(512) void hist_prep_kernel(
    const int* __restrict__ idx_j,
    const float* __restrict__ piW2, const float* __restrict__ pib1,
    const float* __restrict__ pib2,
    const float* __restrict__ piW3, const float* __restrict__ iiW1,
    const float* __restrict__ iiW2,
    int* __restrict__ counts, float* __restrict__ b12,
    unsigned short* __restrict__ Bpack, unsigned short* __restrict__ W2pack) {
  int bid = blockIdx.x;
  int tid = threadIdx.x;
  if (bid < 1563) {  // hist
    int e = bid * 512 + tid;
    if (e < N_EDGES) atomicAdd(&counts[idx_j[e]], 1);
    return;
  }
  int gid = (bid - 1563) * 512 + tid;
  if (gid < 32768) {
    int j = gid & 7;
    int lane = (gid >> 3) & 63;
    int ct = (gid >> 9) & 3;
    int ks = gid >> 11;
    int kidx = ks * 32 + ((lane >> 4) << 3) + j;
    int col = ct * 16 + (lane & 15);
    int k = kidx >> 3, b = kidx & 7;
    float acc = 0.f;
    #pragma unroll 8
    for (int mm = 0; mm < 64; ++mm)
      acc = fmaf(piW3[k * 512 + mm * 8 + b], iiW1[mm * 64 + col], acc);
    Bpack[gid] = f2bf_rne(acc);
  } else if (gid < 32832) {
    int c = gid - 32768;
    float acc = pib2[c];
    for (int k = 0; k < 64; ++k) acc = fmaf(pib1[k], piW2[k * 64 + c], acc);
    b12[c] = acc;
  } else if (gid < 36928) {
    int g2 = gid - 32832;
    int j = g2 & 7;
    int lane = (g2 >> 3) & 63;
    int ct = (g2 >> 9) & 3;
    int ks = g2 >> 11;
    int kidx = ks * 32 + ((lane >> 4) << 3) + j;
    int col = ct * 16 + (lane & 15);
    W2pack[g2] = f2bf_rne(iiW2[kidx * 64 + col]);
  }
}

// ---------- D2: single-dispatch exclusive scan (block b scans chunk b; redundant base)
__global__ __launch_bounds__(1024) void scan_kernel(
    const int* __restrict__ counts, int* __restrict__ cursors) {
  __shared__ int buf[1024];
  __shared__ int red[16];
  int b = blockIdx.x, tid = threadIdx.x;
  int idx = b * 1024 + tid;
  int v = counts[idx];
  buf[tid] = v;
  int partial = 0;
  for (int i = tid; i < b * 1024; i += 1024) partial += counts[i];
  #pragma unroll
  for (int off = 32; off >= 1; off >>= 1) partial += __shfl_down(partial, off, 64);
  if ((tid & 63) == 0) red[tid >> 6] = partial;
  __syncthreads();
  for (int off = 1; off < 1024; off <<= 1) {
    int t = (tid >= off) ? buf[tid - off] : 0;
    __syncthreads();
    buf[tid] += t;
    __syncthreads();
  }
  int base = 0;
  #pragma unroll
  for (int i = 0; i < 16; ++i) base += red[i];
  cursors[idx] = base + buf[tid] - v;
}

// ---------- D3: node MLP (MFMA, 128 nodes / 512-thread block) fused with sort-scatter.
// blocks [0,391): node -> qa,qb ; blocks [391,1954): scatter edges into j-sorted order
__global__ __launch_bounds__(512) void node_scatter_kernel(
    const float* __restrict__ p,
    const int* __restrict__ idx_i, const int* __restrict__ idx_j,
    const float* __restrict__ ppW1, const float* __restrict__ ppb1,
    const float* __restrict__ ppW2, const float* __restrict__ ppb2,
    const float* __restrict__ piW1, const float* __restrict__ piW2,
    int* __restrict__ cursors,
    float* __restrict__ qa, float* __restrict__ qb,
    int2* __restrict__ sorted_ij, int* __restrict__ sorted_e) {
  int bid = blockIdx.x;
  int tid = threadIdx.x;

  if (bid >= 391) {  // ---------------- scatter
    int e = (bid - 391) * 512 + tid;
    if (e < N_EDGES) {
      int j = idx_j[e];
      int pos = atomicAdd(&cursors[j], 1);
      sorted_ij[pos] = make_int2(idx_i[e], j);
      sorted_e[pos] = e;
    }
    return;
  }

  // ---------------- node (MFMA), 128 nodes, 8 waves
  __shared__ __align__(16) unsigned short sBpk[2][4096];  // 16 KB
  __shared__ __align__(16) unsigned short sAct[2][8192];  // 32 KB

  int w = tid >> 6, l = tid & 63;
  int m = l & 15;
  int nb0 = bid * 128;

  for (int t = tid; t < 2048; t += 512) {
    int row = t >> 4, q = t & 15;
    int g = nb0 + row;
    float4 v = make_float4(0.f, 0.f, 0.f, 0.f);
    if (g < N_NODES) v = ((const float4*)p)[g * 16 + q];
    unsigned u0, u1;
    asm("v_cvt_pk_bf16_f32 %0, %1, %2" : "=v"(u0) : "v"(v.x), "v"(v.y));
    asm("v_cvt_pk_bf16_f32 %0, %1, %2" : "=v"(u1) : "v"(v.z), "v"(v.w));
    int sw = (row & 7) << 3;
    *(uint2*)(&sAct[0][row * 64 + ((q * 4) ^ sw)]) = make_uint2(u0, u1);
  }
  packW(ppW1, sBpk[0], tid);
  packW(ppW2, sBpk[1], tid);
  __syncthreads();

  f32x4 acc[4];
  // A: h = tanh(X@ppW1 + b1) -> sAct[1]
  #pragma unroll
  for (int ct = 0; ct < 4; ++ct) {
    float bv = ppb1[ct * 16 + m];
    acc[ct] = (f32x4){bv, bv, bv, bv};
  }
  mfma_gemm(sAct[0], sBpk[0], w, l, acc);
  store_act(sAct[1], w, l, acc, true);
  __syncthreads();

  // B: p1 = h@ppW2 + b2 -> sAct[0]
  #pragma unroll
  for (int ct = 0; ct < 4; ++ct) {
    float bv = ppb2[ct * 16 + m];
    acc[ct] = (f32x4){bv, bv, bv, bv};
  }
  mfma_gemm(sAct[1], sBpk[1], w, l, acc);
  store_act(sAct[0], w, l, acc, false);
  __syncthreads();

  packW(piW1, sBpk[0], tid);
  packW(piW2, sBpk[1], tid);
  __syncthreads();

  // C: t1 = p1@piW1a -> sAct[1]
  #pragma unroll
  for (int ct = 0; ct < 4; ++ct) acc[ct] = (f32x4){0.f, 0.f, 0.f, 0.f};
  mfma_gemm(sAct[0], sBpk[0], w, l, acc);
  store_act(sAct[1], w, l, acc, false);
  __syncthreads();

  // E: qa = t1@piW2 -> global ; repack slot0 = piW1b
  #pragma unroll
  for (int ct = 0; ct < 4; ++ct) acc[ct] = (f32x4){0.f, 0.f, 0.f, 0.f};
  mfma_gemm(sAct[1], sBpk[1], w, l, acc);
  {
    int s = l >> 4;
    #pragma unroll
    for (int ct = 0; ct < 4; ++ct)
      #pragma unroll
      for (int r = 0; r < 4; ++r) {
        int rg = nb0 + w * 16 + s * 4 + r;
        if (rg < N_NODES) qa[(size_t)rg * 64 + ct * 16 + m] = acc[ct][r];
      }
  }
  packW(piW1 + 4096, sBpk[0], tid);
  __syncthreads();

  // D: t2 = p1@piW1b -> sAct[1]
  #pragma unroll
  for (int ct = 0; ct < 4; ++ct) acc[ct] = (f32x4){0.f, 0.f, 0.f, 0.f};
  mfma_gemm(sAct[0], sBpk[0], w, l, acc);
  store_act(sAct[1], w, l, acc, false);
  __syncthreads();

  // F: qb = t2@piW2 -> global
  #pragma unroll
  for (int ct = 0; ct < 4; ++ct) acc[ct] = (f32x4){0.f, 0.f, 0.f, 0.f};
  mfma_gemm(sAct[1], sBpk[1], w, l, acc);
  {
    int s = l >> 4;
    #pragma unroll
    for (int ct = 0; ct < 4; ++ct)
      #pragma unroll
      for (int r = 0; r < 4; ++r) {
        int rg = nb0 + w * 16 + s * 4 + r;
        if (rg < N_NODES) qb[(size_t)rg * 64 + ct * 16 + m] = acc[ct][r];
      }
  }
}

// ---------- D4: edge (j-sorted), 1024 threads = 16 waves, 256 edges/block.
// Round-9 structure; A-pack uses NAMED f32x2 vars (v_pk_mul_f32, no array -> no scratch).
__global__ __launch_bounds__(1024, 8) void edge_kernel(
    const int2* __restrict__ sorted_ij, const int* __restrict__ sorted_e,
    const float* __restrict__ basis,
    const float* __restrict__ qa, const float* __restrict__ qb,
    const float* __restrict__ b12,
    const unsigned short* __restrict__ Bpack,
    const unsigned short* __restrict__ W2pack,
    const float* __restrict__ iib1, const float* __restrict__ iib2,
    float* __restrict__ out) {
  __shared__ __align__(16) unsigned short sB[32768];  // 64 KB
  float* sH2 = (float*)sB;
  unsigned short* sT = sB;
  float* sF = (float*)sB;

  int tid = threadIdx.x;
  int e0 = blockIdx.x * 256;
  int w = tid >> 6, l = tid & 63;
  int m = l & 15, s = l >> 4;
  int eloc = w * 16 + m;
  int swz = (eloc & 7) << 3;

  // ---- issue long-latency loads first (T14): Bpack (L2) + basis (random)
  const uint4* gB = (const uint4*)Bpack;
  uint4 bp0 = gB[tid];
  uint4 bp1 = gB[tid + 1024];
  uint4 bp2 = gB[tid + 2048];
  uint4 bp3 = gB[tid + 3072];
  int eorig = sorted_e[e0 + eloc];
  const float4* bpt = (const float4*)(basis + (size_t)eorig * 8);
  float4 bas01 = bpt[0];
  float4 bas23 = bpt[1];

  // ---- phase 0: gather h2 into LDS (f32, XOR-swizzled). qb rows L1-hot (sorted j).
  for (int t = tid; t < 4096; t += 1024) {
    int e = t >> 4, q = t & 15;
    int2 se = sorted_ij[e0 + e];
    float4 va = ((const float4*)qa)[se.x * 16 + q];
    float4 vb = ((const float4*)qb)[se.y * 16 + q];
    float4 vc = ((const float4*)b12)[q];
    float4 h;
    h.x = va.x + vb.x + vc.x;
    h.y = va.y + vb.y + vc.y;
    h.z = va.z + vb.z + vc.z;
    h.w = va.w + vb.w + vc.w;
    int dw = e * 64 + ((q * 4) ^ ((e & 7) << 3));
    *((float4*)(sH2 + dw)) = h;
  }
  __syncthreads();

  float h2r[16];
  #pragma unroll
  for (int t = 0; t < 16; ++t) h2r[t] = sH2[eloc * 64 + ((t * 4 + s) ^ swz)];

  // named f32x2 registers (NOT an array -> cannot be demoted to scratch)
  f32x2 bs0 = (f32x2){bas01.x, bas01.y};
  f32x2 bs1 = (f32x2){bas01.z, bas01.w};
  f32x2 bs2 = (f32x2){bas23.x, bas23.y};
  f32x2 bs3 = (f32x2){bas23.z, bas23.w};
  __syncthreads();  // all h2 reads done before Bpack overwrite

  // ---- write prefetched Bpack into LDS
  {
    uint4* d = (uint4*)sB;
    d[tid] = bp0;
    d[tid + 1024] = bp1;
    d[tid + 2048] = bp2;
    d[tid + 3072] = bp3;
  }
  __syncthreads();

  f32x4 c0, c1, c2, c3;
  {
    float v0 = iib1[m], v1 = iib1[16 + m], v2 = iib1[32 + m], v3 = iib1[48 + m];
    c0 = (f32x4){v0, v0, v0, v0};
    c1 = (f32x4){v1, v1, v1, v1};
    c2 = (f32x4){v2, v2, v2, v2};
    c3 = (f32x4){v3, v3, v3, v3};
  }

  // ---- main K-loop: 16 K-steps x 4 col-tiles; A-pack = 4 pk_mul + 4 cvt_pk
  const bf16x8* Bl = (const bf16x8*)sB;
  #pragma unroll
  for (int ks = 0; ks < 16; ++ks) {
    bf16x8 B0 = Bl[(ks * 4 + 0) * 64 + l];
    bf16x8 B1 = Bl[(ks * 4 + 1) * 64 + l];
    bf16x8 B2 = Bl[(ks * 4 + 2) * 64 + l];
    bf16x8 B3 = Bl[(ks * 4 + 3) * 64 + l];
    float hv = h2r[ks];
    f32x2 hv2 = (f32x2){hv, hv};
    f32x2 p0 = hv2 * bs0;
    f32x2 p1 = hv2 * bs1;
    f32x2 p2 = hv2 * bs2;
    f32x2 p3 = hv2 * bs3;
    union { unsigned u[4]; bf16x8 v; } A;
    asm("v_cvt_pk_bf16_f32 %0, %1, %2" : "=v"(A.u[0]) : "v"(p0[0]), "v"(p0[1]));
    asm("v_cvt_pk_bf16_f32 %0, %1, %2" : "=v"(A.u[1]) : "v"(p1[0]), "v"(p1[1]));
    asm("v_cvt_pk_bf16_f32 %0, %1, %2" : "=v"(A.u[2]) : "v"(p2[0]), "v"(p2[1]));
    asm("v_cvt_pk_bf16_f32 %0, %1, %2" : "=v"(A.u[3]) : "v"(p3[0]), "v"(p3[1]));
    c0 = __builtin_amdgcn_mfma_f32_16x16x32_bf16(A.v, B0, c0, 0, 0, 0);
    c1 = __builtin_amdgcn_mfma_f32_16x16x32_bf16(A.v, B1, c1, 0, 0, 0);
    c2 = __builtin_amdgcn_mfma_f32_16x16x32_bf16(A.v, B2, c2, 0, 0, 0);
    c3 = __builtin_amdgcn_mfma_f32_16x16x32_bf16(A.v, B3, c3, 0, 0, 0);
  }
  __syncthreads();  // all waves done reading Bpack

  // ---- tanh -> t tile (bf16). D layout: col = ct*16+m, row(local) = s*4+r
  #pragma unroll
  for (int r = 0; r < 4; ++r) {
    int row = w * 16 + s * 4 + r;
    sT[row * 72 + 0 * 16 + m] = f2bf_rne(fast_tanh(c0[r]));
    sT[row * 72 + 1 * 16 + m] = f2bf_rne(fast_tanh(c1[r]));
    sT[row * 72 + 2 * 16 + m] = f2bf_rne(fast_tanh(c2[r]));
    sT[row * 72 + 3 * 16 + m] = f2bf_rne(fast_tanh(c3[r]));
  }
  __syncthreads();

  // ---- second GEMM: i2 = t @ ii_W2 + ii_b2 (K=64: 2 K-steps x 4 col-tiles)
  f32x4 d0, d1, d2, d3;
  {
    float v0 = iib2[m], v1 = iib2[16 + m], v2 = iib2[32 + m], v3 = iib2[48 + m];
    d0 = (f32x4){v0, v0, v0, v0};
    d1 = (f32x4){v1, v1, v1, v1};
    d2 = (f32x4){v2, v2, v2, v2};
    d3 = (f32x4){v3, v3, v3, v3};
  }
  const bf16x8* Wl = (const bf16x8*)W2pack;
  #pragma unroll
  for (int ks = 0; ks < 2; ++ks) {
    bf16x8 Af = *(const bf16x8*)(sT + eloc * 72 + ks * 32 + s * 8);
    d0 = __builtin_amdgcn_mfma_f32_16x16x32_bf16(Af, Wl[(ks * 4 + 0) * 64 + l], d0, 0, 0, 0);
    d1 = __builtin_amdgcn_mfma_f32_16x16x32_bf16(Af, Wl[(ks * 4 + 1) * 64 + l], d1, 0, 0, 0);
    d2 = __builtin_amdgcn_mfma_f32_16x16x32_bf16(Af, Wl[(ks * 4 + 2) * 64 + l], d2, 0, 0, 0);
    d3 = __builtin_amdgcn_mfma_f32_16x16x32_bf16(Af, Wl[(ks * 4 + 3) * 64 + l], d3, 0, 0, 0);
  }

  // ---- phase 3: run-aggregated scatter (two 128-edge halves through LDS)
  #pragma unroll
  for (int h = 0; h < 2; ++h) {
    __syncthreads();
    if ((w >> 3) == h) {
      int wl = w & 7;
      #pragma unroll
      for (int r = 0; r < 4; ++r) {
        int row = wl * 16 + s * 4 + r;
        sF[row * 68 + 0  + m] = d0[r];
        sF[row * 68 + 16 + m] = d1[r];
        sF[row * 68 + 32 + m] = d2[r];
        sF[row * 68 + 48 + m] = d3[r];
      }
    }
    __syncthreads();
    {
      int base_e = e0 + h * 128 + w * 8;
      float acc = sF[(w * 8) * 68 + l];
      int cur_j = sorted_ij[base_e].y;
      #pragma unroll
      for (int rr = 1; rr < 8; ++rr) {
        int nj = sorted_ij[base_e + rr].y;
        float v = sF[(w * 8 + rr) * 68 + l];
        if (nj == cur_j) {
          acc += v;
        } else {
          atomicAdd(&out[(size_t)cur_j * 64 + l], acc);
          acc = v;
          cur_j = nj;
        }
      }
      atomicAdd(&out[(size_t)cur_j * 64 + l], acc);
    }
  }
}

extern "C" void kernel_launch(void* const* d_in, const int* in_sizes, int n_in,
                              void* d_out, int out_size, void* d_ws, size_t ws_size,
                              hipStream_t stream) {
  const float* p     = (const float*)d_in[0];
  const int*   idx_i = (const int*)d_in[1];
  const int*   idx_j = (const int*)d_in[2];
  const float* basis = (const float*)d_in[3];
  const float* ppW1  = (const float*)d_in[4];
  const float* ppb1  = (const float*)d_in[5];
  const float* ppW2  = (const float*)d_in[6];
  const float* ppb2  = (const float*)d_in[7];
  const float* piW1  = (const float*)d_in[8];
  const float* pib1  = (const float*)d_in[9];
  const float* piW2  = (const float*)d_in[10];
  const float* pib2  = (const float*)d_in[11];
  const float* piW3  = (const float*)d_in[12];
  const float* iiW1  = (const float*)d_in[13];
  const float* iib1  = (const float*)d_in[14];
  const float* iiW2  = (const float*)d_in[15];
  const float* iib2  = (const float*)d_in[16];

  float* ws  = (float*)d_ws;
  float* qa  = ws;                          // 3,200,000 f
  float* qb  = ws + 3200000;                // 3,200,000 f
  float* b12 = ws + 6400000;                // 64 f
  unsigned short* Bpack  = (unsigned short*)(ws + 6400064);   // 32768 bf16 (16384 f)
  unsigned short* W2pack = (unsigned short*)(ws + 6416448);   // 4096 bf16 (2048 f)
  int* counts    = (int*)(ws + 6418496);    // NPAD ints
  int* cursors   = (int*)(ws + 6468672);    // NPAD ints
  int2* sorted_ij = (int2*)(ws + 6518848);  // 800000 int2 (8B-aligned)
  int* sorted_e   = (int*)(ws + 8118848);   // 800000 ints (end ~35.7 MB)

  hipMemsetAsync(d_out, 0, (size_t)out_size * sizeof(float), stream);
  hipMemsetAsync(counts, 0, (size_t)NPAD * sizeof(int), stream);
  hist_prep_kernel<<<1636, 512, 0, stream>>>(idx_j, piW2, pib1, pib2,
                                             piW3, iiW1, iiW2,
                                             counts, b12, Bpack, W2pack);
  scan_kernel<<<49, 1024, 0, stream>>>(counts, cursors);
  node_scatter_kernel<<<1954, 512, 0, stream>>>(p, idx_i, idx_j,
                                                ppW1, ppb1, ppW2, ppb2,
                                                piW1, piW2, cursors,
                                                qa, qb, sorted_ij, sorted_e);
  edge_kernel<<<3125, 1024, 0, stream>>>(sorted_ij, sorted_e, basis,
                                         qa, qb, b12, Bpack, W2pack,
                                         iib1, iib2, (float*)d_out);
}

// Round 13
// 242.313 us; speedup vs baseline: 1.1186x; 1.1144x over previous
//
#include <hip/hip_runtime.h>

#define N_NODES 50000
#define N_EDGES 800000
#define NPAD 50176   // 49 * 1024, padded histogram size

typedef float f32x4 __attribute__((ext_vector_type(4)));
typedef short bf16x8 __attribute__((ext_vector_type(8)));

__device__ __forceinline__ float fast_tanh(float x) {
  // tanh(x) = 1 - 2/(exp(2x)+1); v_rcp_f32 (1 ulp) instead of IEEE div sequence
  float e = __expf(2.0f * x);
  float r;
  asm("v_rcp_f32 %0, %1" : "=v"(r) : "v"(e + 1.0f));
  return fmaf(-2.0f, r, 1.0f);
}

__device__ __forceinline__ unsigned short f2bf_rne(float x) {
  unsigned u = __float_as_uint(x);
  unsigned r = u + 0x7FFFu + ((u >> 16) & 1u);
  return (unsigned short)(r >> 16);
}

// ---- pack a 64x64 f32 weight (row-major W[k][col]) into MFMA B-fragment order, bf16
__device__ __forceinline__ void packW(const float* __restrict__ W,
                                      unsigned short* __restrict__ dst, int tid) {
  int ks = tid >> 8, ct = (tid >> 6) & 3, lane = tid & 63;
  int k0 = ks * 32 + ((lane >> 4) << 3);
  int col = ct * 16 + (lane & 15);
  const float* src = W + k0 * 64 + col;
  unsigned u[4];
  #pragma unroll
  for (int jj = 0; jj < 4; ++jj) {
    float v0 = src[(2 * jj) * 64];
    float v1 = src[(2 * jj + 1) * 64];
    asm("v_cvt_pk_bf16_f32 %0, %1, %2" : "=v"(u[jj]) : "v"(v0), "v"(v1));
  }
  *(uint4*)(dst + (size_t)tid * 8) = make_uint4(u[0], u[1], u[2], u[3]);
}

// ---- one 128x64x64 GEMM step on MFMA: acc[ct] += ActIn(16 rows of wave w) @ Bpk
__device__ __forceinline__ void mfma_gemm(const unsigned short* __restrict__ actIn,
                                          const unsigned short* __restrict__ bpk,
                                          int w, int l, f32x4 acc[4]) {
  int m = l & 15, s = l >> 4;
  int row = w * 16 + m;
  int sw = (m & 7) << 3;
  #pragma unroll
  for (int ks = 0; ks < 2; ++ks) {
    bf16x8 a = *(const bf16x8*)(actIn + row * 64 + ((ks * 32 + s * 8) ^ sw));
    #pragma unroll
    for (int ct = 0; ct < 4; ++ct) {
      bf16x8 b = *(const bf16x8*)(bpk + ((size_t)((ks * 4 + ct) * 64 + l)) * 8);
      acc[ct] = __builtin_amdgcn_mfma_f32_16x16x32_bf16(a, b, acc[ct], 0, 0, 0);
    }
  }
}

// ---- write MFMA C (col=ct*16+m, row=s*4+r) to a bf16 act tile (swizzled), opt tanh
__device__ __forceinline__ void store_act(unsigned short* __restrict__ actOut,
                                          int w, int l, const f32x4 acc[4],
                                          bool do_tanh) {
  int m = l & 15, s = l >> 4;
  #pragma unroll
  for (int ct = 0; ct < 4; ++ct) {
    #pragma unroll
    for (int r = 0; r < 4; ++r) {
      int row = w * 16 + s * 4 + r;
      float v = acc[ct][r];
      if (do_tanh) v = fast_tanh(v);
      actOut[row * 64 + ((ct * 16 + m) ^ ((row & 7) << 3))] = f2bf_rne(v);
    }
  }
}

// ---------- D1: hist + prep (512 threads).  blocks [0,1563): hist ; [1563,1636): prep
__global__ __launch_bounds__(512) void hist_prep_kernel(
    const int* __restrict__ idx_j,
    const float* __restrict__ piW2, const float* __restrict__ pib1,
    const float* __restrict__ pib2,
    const float* __restrict__ piW3, const float* __restrict__ iiW1,
    const float* __restrict__ iiW2,
    int* __restrict__ counts, float* __restrict__ b12,
    unsigned short* __restrict__ Bpack, unsigned short* __restrict__ W2pack) {
  int bid = blockIdx.x;
  int tid = threadIdx.x;
  if (bid < 1563) {  // hist
    int e = bid * 512 + tid;
    if (e < N_EDGES) atomicAdd(&counts[idx_j[e]], 1);
    return;
  }
  int gid = (bid - 1563) * 512 + tid;
  if (gid < 32768) {
    int j = gid & 7;
    int lane = (gid >> 3) & 63;
    int ct = (gid >> 9) & 3;
    int ks = gid >> 11;
    int kidx = ks * 32 + ((lane >> 4) << 3) + j;
    int col = ct * 16 + (lane & 15);
    int k = kidx >> 3, b = kidx & 7;
    float acc = 0.f;
    #pragma unroll 8
    for (int mm = 0; mm < 64; ++mm)
      acc = fmaf(piW3[k * 512 + mm * 8 + b], iiW1[mm * 64 + col], acc);
    Bpack[gid] = f2bf_rne(acc);
  } else if (gid < 32832) {
    int c = gid - 32768;
    float acc = pib2[c];
    for (int k = 0; k < 64; ++k) acc = fmaf(pib1[k], piW2[k * 64 + c], acc);
    b12[c] = acc;
  } else if (gid < 36928) {
    int g2 = gid - 32832;
    int j = g2 & 7;
    int lane = (g2 >> 3) & 63;
    int ct = (g2 >> 9) & 3;
    int ks = g2 >> 11;
    int kidx = ks * 32 + ((lane >> 4) << 3) + j;
    int col = ct * 16 + (lane & 15);
    W2pack[g2] = f2bf_rne(iiW2[kidx * 64 + col]);
  }
}

// ---------- D2: single-dispatch exclusive scan (block b scans chunk b; redundant base)
__global__ __launch_bounds__(1024) void scan_kernel(
    const int* __restrict__ counts, int* __restrict__ cursors) {
  __shared__ int buf[1024];
  __shared__ int red[16];
  int b = blockIdx.x, tid = threadIdx.x;
  int idx = b * 1024 + tid;
  int v = counts[idx];
  buf[tid] = v;
  int partial = 0;
  for (int i = tid; i < b * 1024; i += 1024) partial += counts[i];
  #pragma unroll
  for (int off = 32; off >= 1; off >>= 1) partial += __shfl_down(partial, off, 64);
  if ((tid & 63) == 0) red[tid >> 6] = partial;
  __syncthreads();
  for (int off = 1; off < 1024; off <<= 1) {
    int t = (tid >= off) ? buf[tid - off] : 0;
    __syncthreads();
    buf[tid] += t;
    __syncthreads();
  }
  int base = 0;
  #pragma unroll
  for (int i = 0; i < 16; ++i) base += red[i];
  cursors[idx] = base + buf[tid] - v;
}

// ---------- D3: node MLP (MFMA, 128 nodes / 512-thread block) fused with sort-scatter.
// blocks [0,391): node -> qa, qb(+b12 folded) ; blocks [391,1954): scatter (j-sorted)
__global__ __launch_bounds__(512) void node_scatter_kernel(
    const float* __restrict__ p,
    const int* __restrict__ idx_i, const int* __restrict__ idx_j,
    const float* __restrict__ ppW1, const float* __restrict__ ppb1,
    const float* __restrict__ ppW2, const float* __restrict__ ppb2,
    const float* __restrict__ piW1, const float* __restrict__ piW2,
    const float* __restrict__ b12,
    int* __restrict__ cursors,
    float* __restrict__ qa, float* __restrict__ qb,
    int2* __restrict__ sorted_ij, int* __restrict__ sorted_e) {
  int bid = blockIdx.x;
  int tid = threadIdx.x;

  if (bid >= 391) {  // ---------------- scatter
    int e = (bid - 391) * 512 + tid;
    if (e < N_EDGES) {
      int j = idx_j[e];
      int pos = atomicAdd(&cursors[j], 1);
      sorted_ij[pos] = make_int2(idx_i[e], j);
      sorted_e[pos] = e;
    }
    return;
  }

  // ---------------- node (MFMA), 128 nodes, 8 waves
  __shared__ __align__(16) unsigned short sBpk[2][4096];  // 16 KB
  __shared__ __align__(16) unsigned short sAct[2][8192];  // 32 KB

  int w = tid >> 6, l = tid & 63;
  int m = l & 15;
  int nb0 = bid * 128;

  for (int t = tid; t < 2048; t += 512) {
    int row = t >> 4, q = t & 15;
    int g = nb0 + row;
    float4 v = make_float4(0.f, 0.f, 0.f, 0.f);
    if (g < N_NODES) v = ((const float4*)p)[g * 16 + q];
    unsigned u0, u1;
    asm("v_cvt_pk_bf16_f32 %0, %1, %2" : "=v"(u0) : "v"(v.x), "v"(v.y));
    asm("v_cvt_pk_bf16_f32 %0, %1, %2" : "=v"(u1) : "v"(v.z), "v"(v.w));
    int sw = (row & 7) << 3;
    *(uint2*)(&sAct[0][row * 64 + ((q * 4) ^ sw)]) = make_uint2(u0, u1);
  }
  packW(ppW1, sBpk[0], tid);
  packW(ppW2, sBpk[1], tid);
  __syncthreads();

  f32x4 acc[4];
  // A: h = tanh(X@ppW1 + b1) -> sAct[1]
  #pragma unroll
  for (int ct = 0; ct < 4; ++ct) {
    float bv = ppb1[ct * 16 + m];
    acc[ct] = (f32x4){bv, bv, bv, bv};
  }
  mfma_gemm(sAct[0], sBpk[0], w, l, acc);
  store_act(sAct[1], w, l, acc, true);
  __syncthreads();

  // B: p1 = h@ppW2 + b2 -> sAct[0]
  #pragma unroll
  for (int ct = 0; ct < 4; ++ct) {
    float bv = ppb2[ct * 16 + m];
    acc[ct] = (f32x4){bv, bv, bv, bv};
  }
  mfma_gemm(sAct[1], sBpk[1], w, l, acc);
  store_act(sAct[0], w, l, acc, false);
  __syncthreads();

  packW(piW1, sBpk[0], tid);
  packW(piW2, sBpk[1], tid);
  __syncthreads();

  // C: t1 = p1@piW1a -> sAct[1]
  #pragma unroll
  for (int ct = 0; ct < 4; ++ct) acc[ct] = (f32x4){0.f, 0.f, 0.f, 0.f};
  mfma_gemm(sAct[0], sBpk[0], w, l, acc);
  store_act(sAct[1], w, l, acc, false);
  __syncthreads();

  // E: qa = t1@piW2 -> global ; repack slot0 = piW1b
  #pragma unroll
  for (int ct = 0; ct < 4; ++ct) acc[ct] = (f32x4){0.f, 0.f, 0.f, 0.f};
  mfma_gemm(sAct[1], sBpk[1], w, l, acc);
  {
    int s = l >> 4;
    #pragma unroll
    for (int ct = 0; ct < 4; ++ct)
      #pragma unroll
      for (int r = 0; r < 4; ++r) {
        int rg = nb0 + w * 16 + s * 4 + r;
        if (rg < N_NODES) qa[(size_t)rg * 64 + ct * 16 + m] = acc[ct][r];
      }
  }
  packW(piW1 + 4096, sBpk[0], tid);
  __syncthreads();

  // D: t2 = p1@piW1b -> sAct[1]
  #pragma unroll
  for (int ct = 0; ct < 4; ++ct) acc[ct] = (f32x4){0.f, 0.f, 0.f, 0.f};
  mfma_gemm(sAct[0], sBpk[0], w, l, acc);
  store_act(sAct[1], w, l, acc, false);
  __syncthreads();

  // F: qb = t2@piW2 + b12 -> global (b12 folded here; edge gather drops it)
  #pragma unroll
  for (int ct = 0; ct < 4; ++ct) acc[ct] = (f32x4){0.f, 0.f, 0.f, 0.f};
  mfma_gemm(sAct[1], sBpk[1], w, l, acc);
  {
    int s = l >> 4;
    #pragma unroll
    for (int ct = 0; ct < 4; ++ct) {
      float bv = b12[ct * 16 + m];
      #pragma unroll
      for (int r = 0; r < 4; ++r) {
        int rg = nb0 + w * 16 + s * 4 + r;
        if (rg < N_NODES) qb[(size_t)rg * 64 + ct * 16 + m] = acc[ct][r] + bv;
      }
    }
  }
}

// ---------- D4: edge (j-sorted), 1024 threads = 16 waves, 256 edges/block.
// Round-9 structure and A-pack (scalar muls — the only variant with clean counters).
__global__ __launch_bounds__(1024, 8) void edge_kernel(
    const int2* __restrict__ sorted_ij, const int* __restrict__ sorted_e,
    const float* __restrict__ basis,
    const float* __restrict__ qa, const float* __restrict__ qb,
    const unsigned short* __restrict__ Bpack,
    const unsigned short* __restrict__ W2pack,
    const float* __restrict__ iib1, const float* __restrict__ iib2,
    float* __restrict__ out) {
  __shared__ __align__(16) unsigned short sB[32768];  // 64 KB
  float* sH2 = (float*)sB;
  unsigned short* sT = sB;
  float* sF = (float*)sB;

  int tid = threadIdx.x;
  int e0 = blockIdx.x * 256;
  int w = tid >> 6, l = tid & 63;
  int m = l & 15, s = l >> 4;
  int eloc = w * 16 + m;
  int swz = (eloc & 7) << 3;

  // ---- issue long-latency loads first (T14): Bpack (L2) + basis (random)
  const uint4* gB = (const uint4*)Bpack;
  uint4 bp0 = gB[tid];
  uint4 bp1 = gB[tid + 1024];
  uint4 bp2 = gB[tid + 2048];
  uint4 bp3 = gB[tid + 3072];
  int eorig = sorted_e[e0 + eloc];
  const float4* bpt = (const float4*)(basis + (size_t)eorig * 8);
  float4 bas01 = bpt[0];
  float4 bas23 = bpt[1];

  // ---- phase 0: gather h2 into LDS (f32, XOR-swizzled). b12 pre-folded into qb.
  for (int t = tid; t < 4096; t += 1024) {
    int e = t >> 4, q = t & 15;
    int2 se = sorted_ij[e0 + e];
    float4 va = ((const float4*)qa)[se.x * 16 + q];
    float4 vb = ((const float4*)qb)[se.y * 16 + q];
    float4 h;
    h.x = va.x + vb.x;
    h.y = va.y + vb.y;
    h.z = va.z + vb.z;
    h.w = va.w + vb.w;
    int dw = e * 64 + ((q * 4) ^ ((e & 7) << 3));
    *((float4*)(sH2 + dw)) = h;
  }
  __syncthreads();

  float h2r[16];
  #pragma unroll
  for (int t = 0; t < 16; ++t) h2r[t] = sH2[eloc * 64 + ((t * 4 + s) ^ swz)];

  float bas[8];
  bas[0] = bas01.x; bas[1] = bas01.y; bas[2] = bas01.z; bas[3] = bas01.w;
  bas[4] = bas23.x; bas[5] = bas23.y; bas[6] = bas23.z; bas[7] = bas23.w;
  __syncthreads();  // all h2 reads done before Bpack overwrite

  // ---- write prefetched Bpack into LDS
  {
    uint4* d = (uint4*)sB;
    d[tid] = bp0;
    d[tid + 1024] = bp1;
    d[tid + 2048] = bp2;
    d[tid + 3072] = bp3;
  }
  __syncthreads();

  f32x4 c0, c1, c2, c3;
  {
    float v0 = iib1[m], v1 = iib1[16 + m], v2 = iib1[32 + m], v3 = iib1[48 + m];
    c0 = (f32x4){v0, v0, v0, v0};
    c1 = (f32x4){v1, v1, v1, v1};
    c2 = (f32x4){v2, v2, v2, v2};
    c3 = (f32x4){v3, v3, v3, v3};
  }

  // ---- main K-loop: 16 K-steps x 4 col-tiles, rne-bf16 A = 64 MFMA/wave
  const bf16x8* Bl = (const bf16x8*)sB;
  #pragma unroll
  for (int ks = 0; ks < 16; ++ks) {
    bf16x8 B0 = Bl[(ks * 4 + 0) * 64 + l];
    bf16x8 B1 = Bl[(ks * 4 + 1) * 64 + l];
    bf16x8 B2 = Bl[(ks * 4 + 2) * 64 + l];
    bf16x8 B3 = Bl[(ks * 4 + 3) * 64 + l];
    float hv = h2r[ks];
    union { unsigned u[4]; bf16x8 v; } A;
    #pragma unroll
    for (int j = 0; j < 4; ++j) {
      float p0 = hv * bas[2 * j];
      float p1 = hv * bas[2 * j + 1];
      asm("v_cvt_pk_bf16_f32 %0, %1, %2" : "=v"(A.u[j]) : "v"(p0), "v"(p1));
    }
    c0 = __builtin_amdgcn_mfma_f32_16x16x32_bf16(A.v, B0, c0, 0, 0, 0);
    c1 = __builtin_amdgcn_mfma_f32_16x16x32_bf16(A.v, B1, c1, 0, 0, 0);
    c2 = __builtin_amdgcn_mfma_f32_16x16x32_bf16(A.v, B2, c2, 0, 0, 0);
    c3 = __builtin_amdgcn_mfma_f32_16x16x32_bf16(A.v, B3, c3, 0, 0, 0);
  }
  __syncthreads();  // all waves done reading Bpack

  // ---- tanh -> t tile (bf16). D layout: col = ct*16+m, row(local) = s*4+r
  #pragma unroll
  for (int r = 0; r < 4; ++r) {
    int row = w * 16 + s * 4 + r;
    sT[row * 72 + 0 * 16 + m] = f2bf_rne(fast_tanh(c0[r]));
    sT[row * 72 + 1 * 16 + m] = f2bf_rne(fast_tanh(c1[r]));
    sT[row * 72 + 2 * 16 + m] = f2bf_rne(fast_tanh(c2[r]));
    sT[row * 72 + 3 * 16 + m] = f2bf_rne(fast_tanh(c3[r]));
  }
  __syncthreads();

  // ---- second GEMM: i2 = t @ ii_W2 + ii_b2 (K=64: 2 K-steps x 4 col-tiles)
  f32x4 d0, d1, d2, d3;
  {
    float v0 = iib2[m], v1 = iib2[16 + m], v2 = iib2[32 + m], v3 = iib2[48 + m];
    d0 = (f32x4){v0, v0, v0, v0};
    d1 = (f32x4){v1, v1, v1, v1};
    d2 = (f32x4){v2, v2, v2, v2};
    d3 = (f32x4){v3, v3, v3, v3};
  }
  const bf16x8* Wl = (const bf16x8*)W2pack;
  #pragma unroll
  for (int ks = 0; ks < 2; ++ks) {
    bf16x8 Af = *(const bf16x8*)(sT + eloc * 72 + ks * 32 + s * 8);
    d0 = __builtin_amdgcn_mfma_f32_16x16x32_bf16(Af, Wl[(ks * 4 + 0) * 64 + l], d0, 0, 0, 0);
    d1 = __builtin_amdgcn_mfma_f32_16x16x32_bf16(Af, Wl[(ks * 4 + 1) * 64 + l], d1, 0, 0, 0);
    d2 = __builtin_amdgcn_mfma_f32_16x16x32_bf16(Af, Wl[(ks * 4 + 2) * 64 + l], d2, 0, 0, 0);
    d3 = __builtin_amdgcn_mfma_f32_16x16x32_bf16(Af, Wl[(ks * 4 + 3) * 64 + l], d3, 0, 0, 0);
  }

  // ---- phase 3: run-aggregated scatter (two 128-edge halves through LDS)
  #pragma unroll
  for (int h = 0; h < 2; ++h) {
    __syncthreads();
    if ((w >> 3) == h) {
      int wl = w & 7;
      #pragma unroll
      for (int r = 0; r < 4; ++r) {
        int row = wl * 16 + s * 4 + r;
        sF[row * 68 + 0  + m] = d0[r];
        sF[row * 68 + 16 + m] = d1[r];
        sF[row * 68 + 32 + m] = d2[r];
        sF[row * 68 + 48 + m] = d3[r];
      }
    }
    __syncthreads();
    {
      int base_e = e0 + h * 128 + w * 8;
      float acc = sF[(w * 8) * 68 + l];
      int cur_j = sorted_ij[base_e].y;
      #pragma unroll
      for (int rr = 1; rr < 8; ++rr) {
        int nj = sorted_ij[base_e + rr].y;
        float v = sF[(w * 8 + rr) * 68 + l];
        if (nj == cur_j) {
          acc += v;
        } else {
          atomicAdd(&out[(size_t)cur_j * 64 + l], acc);
          acc = v;
          cur_j = nj;
        }
      }
      atomicAdd(&out[(size_t)cur_j * 64 + l], acc);
    }
  }
}

extern "C" void kernel_launch(void* const* d_in, const int* in_sizes, int n_in,
                              void* d_out, int out_size, void* d_ws, size_t ws_size,
                              hipStream_t stream) {
  const float* p     = (const float*)d_in[0];
  const int*   idx_i = (const int*)d_in[1];
  const int*   idx_j = (const int*)d_in[2];
  const float* basis = (const float*)d_in[3];
  const float* ppW1  = (const float*)d_in[4];
  const float* ppb1  = (const float*)d_in[5];
  const float* ppW2  = (const float*)d_in[6];
  const float* ppb2  = (const float*)d_in[7];
  const float* piW1  = (const float*)d_in[8];
  const float* pib1  = (const float*)d_in[9];
  const float* piW2  = (const float*)d_in[10];
  const float* pib2  = (const float*)d_in[11];
  const float* piW3  = (const float*)d_in[12];
  const float* iiW1  = (const float*)d_in[13];
  const float* iib1  = (const float*)d_in[14];
  const float* iiW2  = (const float*)d_in[15];
  const float* iib2  = (const float*)d_in[16];

  float* ws  = (float*)d_ws;
  float* qa  = ws;                          // 3,200,000 f
  float* qb  = ws + 3200000;                // 3,200,000 f
  float* b12 = ws + 6400000;                // 64 f
  unsigned short* Bpack  = (unsigned short*)(ws + 6400064);   // 32768 bf16 (16384 f)
  unsigned short* W2pack = (unsigned short*)(ws + 6416448);   // 4096 bf16 (2048 f)
  int* counts    = (int*)(ws + 6418496);    // NPAD ints
  int* cursors   = (int*)(ws + 6468672);    // NPAD ints
  int2* sorted_ij = (int2*)(ws + 6518848);  // 800000 int2 (8B-aligned)
  int* sorted_e   = (int*)(ws + 8118848);   // 800000 ints (end ~35.7 MB)

  hipMemsetAsync(d_out, 0, (size_t)out_size * sizeof(float), stream);
  hipMemsetAsync(counts, 0, (size_t)NPAD * sizeof(int), stream);
  hist_prep_kernel<<<1636, 512, 0, stream>>>(idx_j, piW2, pib1, pib2,
                                             piW3, iiW1, iiW2,
                                             counts, b12, Bpack, W2pack);
  scan_kernel<<<49, 1024, 0, stream>>>(counts, cursors);
  node_scatter_kernel<<<1954, 512, 0, stream>>>(p, idx_i, idx_j,
                                                ppW1, ppb1, ppW2, ppb2,
                                                piW1, piW2, b12, cursors,
                                                qa, qb, sorted_ij, sorted_e);
  edge_kernel<<<3125, 1024, 0, stream>>>(sorted_ij, sorted_e, basis,
                                         qa, qb, Bpack, W2pack,
                                         iib1, iib2, (float*)d_out);
}